// Round 1
// baseline (603.178 us; speedup 1.0000x reference)
//
#include <hip/hip_runtime.h>
#include <math.h>

#define B_ 4
#define N_ 4096
#define E_ 131072
#define ET_ (E_ + N_)   /* 135168 edges incl. self-loops */
#define F_ 768
#define H_ 4
#define D_ 64
#define HD_ 256
#define C_ 6

// ---------------- CSR build (counting sort by dst) ----------------
__global__ void k_count(const int* __restrict__ ei, int* __restrict__ counts){
  int idx = blockIdx.x*256 + threadIdx.x;
  if (idx >= B_*ET_) return;
  int b = idx / ET_, i = idx - b*ET_;
  int dst = (i < E_) ? ei[b*2*E_ + E_ + i] : (i - E_);
  atomicAdd(&counts[b*N_ + dst], 1);
}

__global__ void k_scan(const int* __restrict__ counts, int* __restrict__ offs){
  __shared__ int lds[1024];
  int b = blockIdx.x, t = threadIdx.x;
  int c[4]; int tot = 0;
  #pragma unroll
  for (int j=0;j<4;j++){ c[j] = counts[b*N_ + t*4 + j]; tot += c[j]; }
  lds[t] = tot; __syncthreads();
  for (int off=1; off<1024; off<<=1){
    int u = (t>=off) ? lds[t-off] : 0;
    __syncthreads();
    lds[t] += u;
    __syncthreads();
  }
  int excl = lds[t] - tot;
  int o = excl;
  #pragma unroll
  for (int j=0;j<4;j++){ offs[b*(N_+1) + t*4 + j] = o; o += c[j]; }
  if (t==1023) offs[b*(N_+1) + N_] = o;
}

__global__ void k_scatter(const int* __restrict__ ei, const int* __restrict__ offs,
                          int* __restrict__ cursor, int* __restrict__ srcs){
  int idx = blockIdx.x*256 + threadIdx.x;
  if (idx >= B_*ET_) return;
  int b = idx / ET_, i = idx - b*ET_;
  int src, dst;
  if (i < E_){ src = ei[b*2*E_ + i]; dst = ei[b*2*E_ + E_ + i]; }
  else { src = i - E_; dst = src; }
  int pos = offs[b*(N_+1) + dst] + atomicAdd(&cursor[b*N_ + dst], 1);
  srcs[b*ET_ + pos] = src;
}

// ---------------- fp32 tiled GEMM: O[M,NC] = A[M,K] @ W[K,NC] ----------------
template<int K, int BN, int TN>
__global__ __launch_bounds__(256) void k_gemm(const float* __restrict__ A,
                                              const float* __restrict__ W,
                                              float* __restrict__ O, int NC){
  const int BM=128, BK=16, TM=8;
  __shared__ float As[BK][BM+4];   // transposed A tile, 16B-aligned rows
  __shared__ float Bs[BK][BN+4];
  int t = threadIdx.x;
  int m0 = blockIdx.x*BM, n0 = blockIdx.y*BN;
  int tx = t & 15, ty = t >> 4;
  float acc[TM][TN];
  #pragma unroll
  for (int i=0;i<TM;i++)
    #pragma unroll
    for (int j=0;j<TN;j++) acc[i][j]=0.f;

  for (int k0=0;k0<K;k0+=BK){
    #pragma unroll
    for (int r=0;r<2;r++){            // A tile: 128x16 = 512 float4
      int i = t + r*256;
      int row = i>>2, k4 = (i&3)*4;
      float4 v = *reinterpret_cast<const float4*>(&A[(size_t)(m0+row)*K + k0 + k4]);
      As[k4+0][row]=v.x; As[k4+1][row]=v.y; As[k4+2][row]=v.z; As[k4+3][row]=v.w;
    }
    #pragma unroll
    for (int r=0;r<(BN*BK)/1024;r++){ // B tile
      int i = t + r*256;
      int kr = i/(BN/4), c4 = (i%(BN/4))*4;
      *reinterpret_cast<float4*>(&Bs[kr][c4]) =
        *reinterpret_cast<const float4*>(&W[(size_t)(k0+kr)*NC + n0 + c4]);
    }
    __syncthreads();
    #pragma unroll
    for (int kk=0;kk<BK;kk++){
      float a[TM], bb[TN];
      #pragma unroll
      for (int i=0;i<TM;i++) a[i] = As[kk][ty*TM+i];
      #pragma unroll
      for (int j=0;j<TN;j++) bb[j] = Bs[kk][tx*TN+j];
      #pragma unroll
      for (int i=0;i<TM;i++)
        #pragma unroll
        for (int j=0;j<TN;j++) acc[i][j] = fmaf(a[i], bb[j], acc[i][j]);
    }
    __syncthreads();
  }
  #pragma unroll
  for (int i=0;i<TM;i++){
    float* dst = &O[(size_t)(m0+ty*TM+i)*NC + n0 + tx*TN];
    #pragma unroll
    for (int j=0;j<TN;j+=4){
      float4 v = make_float4(acc[i][j],acc[i][j+1],acc[i][j+2],acc[i][j+3]);
      *reinterpret_cast<float4*>(dst+j) = v;
    }
  }
}

// ---------------- per-node attention coefficients a_s, a_d ----------------
template<int HD, int H>
__global__ void k_attn(const float* __restrict__ h, const float* __restrict__ atts,
                       const float* __restrict__ attd, float* __restrict__ a_s,
                       float* __restrict__ a_d){
  int n = blockIdx.x; int t = threadIdx.x;
  float v = h[(size_t)n*HD + t];
  float ps = v*atts[t], pd = v*attd[t];
  #pragma unroll
  for (int m=32;m>=1;m>>=1){ ps += __shfl_xor(ps,m,64); pd += __shfl_xor(pd,m,64); }
  if ((t&63)==0){ int head = t>>6; a_s[n*H + head]=ps; a_d[n*H + head]=pd; }
}

// ---------------- pull-mode edge-softmax aggregation ----------------
// out[n] = (sum_e exp(leaky(a_s[src]+a_d[n])) * h[src]) / (sum_e exp(...) + 1e-16) + bias, [elu]
template<int HD, int H, bool ELU>
__global__ void k_aggr(const float* __restrict__ h, const float* __restrict__ a_s,
                       const float* __restrict__ a_d, const int* __restrict__ srcs,
                       const int* __restrict__ offs, const float* __restrict__ bias,
                       float* __restrict__ out){
  int ng = blockIdx.x;             // b*N + n
  int b = ng >> 12, n = ng & (N_-1);
  int t = threadIdx.x;
  int head = t >> 6;               // HD=64 -> head 0
  int st = offs[b*(N_+1)+n], en = offs[b*(N_+1)+n+1];
  float adv = a_d[ng*H + head];
  float acc = 0.f, psum = 0.f;
  const int*   sp  = &srcs[(size_t)b*ET_];
  const float* hb  = &h[(size_t)b*N_*HD];
  const float* asb = &a_s[(size_t)b*N_*H];
  for (int i=st;i<en;i++){
    int s = sp[i];
    float e = asb[s*H + head] + adv;
    e = e > 0.f ? e : 0.2f*e;
    float p = __expf(e);
    acc = fmaf(p, hb[(size_t)s*HD + t], acc);
    psum += p;
  }
  float val = acc/(psum + 1e-16f) + bias[t];
  if (ELU) val = val > 0.f ? val : expm1f(val);
  out[(size_t)ng*HD + t] = val;
}

// ---------------- node-mean reduction ----------------
__global__ void k_reduce(const float* __restrict__ x3, float* __restrict__ embed){
  __shared__ float red[256];
  int bid = blockIdx.x; int b = bid>>4, chunk = bid & 15;
  int t = threadIdx.x; int col = t & 63, q = t>>6;
  float s = 0.f;
  int r0 = chunk*256 + q*64;
  const float* p = &x3[((size_t)b*N_ + r0)*64 + col];
  for (int j=0;j<64;j++) s += p[(size_t)j*64];
  red[t]=s; __syncthreads();
  if (t<64){
    float v = red[t]+red[t+64]+red[t+128]+red[t+192];
    atomicAdd(&embed[b*64+t], v);
  }
}

// ---------------- classifier + log_softmax + loss + argmax ----------------
__global__ void k_final(const float* __restrict__ embed, const float* __restrict__ Wc,
                        const float* __restrict__ bc, const int* __restrict__ labels,
                        float* __restrict__ out){
  __shared__ float lg[B_][C_];
  __shared__ float lossv[B_];
  int t = threadIdx.x;
  if (t < B_*C_){
    int b = t / C_, c = t - b*C_;
    float s = 0.f;
    for (int k=0;k<64;k++) s += embed[b*64+k]*Wc[k*C_+c];
    lg[b][c] = s*(1.0f/N_) + bc[c];
  }
  __syncthreads();
  if (t < B_){
    int b = t;
    float mx = lg[b][0]; int pred = 0;
    for (int c=1;c<C_;c++) if (lg[b][c] > mx){ mx = lg[b][c]; pred = c; }
    float se = 0.f;
    for (int c=0;c<C_;c++) se += expf(lg[b][c]-mx);
    float lse = mx + logf(se);
    int lab = labels[b];
    lossv[b] = lse - lg[b][lab];
    out[b]      = (float)pred;
    out[B_+b]   = (float)lab;
  }
  __syncthreads();
  if (t==0) out[8] = 0.25f*(lossv[0]+lossv[1]+lossv[2]+lossv[3]);
}

extern "C" void kernel_launch(void* const* d_in, const int* in_sizes, int n_in,
                              void* d_out, int out_size, void* d_ws, size_t ws_size,
                              hipStream_t stream){
  const float* x0     = (const float*)d_in[0];
  const int*   labels = (const int*)d_in[1];
  const int*   ei     = (const int*)d_in[2];
  const float* W1=(const float*)d_in[3],  *as1=(const float*)d_in[4],
             *ad1=(const float*)d_in[5],  *b1 =(const float*)d_in[6];
  const float* W2=(const float*)d_in[7],  *as2=(const float*)d_in[8],
             *ad2=(const float*)d_in[9],  *b2 =(const float*)d_in[10];
  const float* W3=(const float*)d_in[11], *as3=(const float*)d_in[12],
             *ad3=(const float*)d_in[13], *b3 =(const float*)d_in[14];
  const float* Wc=(const float*)d_in[15], *bc =(const float*)d_in[16];
  float* out = (float*)d_out;

  char* ws = (char*)d_ws;
  size_t off = 0;
  auto alloc = [&](size_t bytes)->void*{ void* p = ws + off; off += (bytes + 255) & ~(size_t)255; return p; };
  float* hbuf   = (float*)alloc((size_t)B_*N_*HD_*4);
  float* xcur   = (float*)alloc((size_t)B_*N_*HD_*4);
  float* a_s    = (float*)alloc((size_t)B_*N_*H_*4);
  float* a_d    = (float*)alloc((size_t)B_*N_*H_*4);
  int*   counts = (int*)alloc((size_t)B_*N_*4);
  int*   offs   = (int*)alloc((size_t)B_*(N_+1)*4);
  int*   cursor = (int*)alloc((size_t)B_*N_*4);
  int*   srcs   = (int*)alloc((size_t)B_*ET_*4);
  float* embed  = (float*)alloc((size_t)B_*64*4);

  hipMemsetAsync(counts, 0, (size_t)B_*N_*4, stream);
  hipMemsetAsync(cursor, 0, (size_t)B_*N_*4, stream);
  hipMemsetAsync(embed,  0, (size_t)B_*64*4, stream);

  int nb = (B_*ET_ + 255)/256;
  k_count  <<<nb, 256, 0, stream>>>(ei, counts);
  k_scan   <<<B_, 1024, 0, stream>>>(counts, offs);
  k_scatter<<<nb, 256, 0, stream>>>(ei, offs, cursor, srcs);

  // layer 1: 768 -> 4x64, concat, elu
  k_gemm<768,128,8><<<dim3(B_*N_/128, 2), 256, 0, stream>>>(x0, W1, hbuf, 256);
  k_attn<256,4>    <<<B_*N_, 256, 0, stream>>>(hbuf, as1, ad1, a_s, a_d);
  k_aggr<256,4,true><<<B_*N_, 256, 0, stream>>>(hbuf, a_s, a_d, srcs, offs, b1, xcur);
  // layer 2: 256 -> 4x64, concat, elu
  k_gemm<256,128,8><<<dim3(B_*N_/128, 2), 256, 0, stream>>>(xcur, W2, hbuf, 256);
  k_attn<256,4>    <<<B_*N_, 256, 0, stream>>>(hbuf, as2, ad2, a_s, a_d);
  k_aggr<256,4,true><<<B_*N_, 256, 0, stream>>>(hbuf, a_s, a_d, srcs, offs, b2, xcur);
  // layer 3: 256 -> 64, 1 head, mean(=identity), no elu
  k_gemm<256,64,4> <<<dim3(B_*N_/128, 1), 256, 0, stream>>>(xcur, W3, hbuf, 64);
  k_attn<64,1>     <<<B_*N_, 64, 0, stream>>>(hbuf, as3, ad3, a_s, a_d);
  k_aggr<64,1,false><<<B_*N_, 64, 0, stream>>>(hbuf, a_s, a_d, srcs, offs, b3, xcur);

  k_reduce<<<B_*16, 256, 0, stream>>>(xcur, embed);
  k_final <<<1, 64, 0, stream>>>(embed, Wc, bc, labels, out);
}